// Round 1
// baseline (49458.853 us; speedup 1.0000x reference)
//
#include <hip/hip_runtime.h>
#include <math.h>

#define Bsz 512
#define Tsz 1024
#define Vsz 27
#define Hsz 512

// ---- one GRU timestep ----
// grid (16 batch-tiles, 16 hp-tiles), block 256.
// Block (bt, j): computes h_next[32 batch rows x 32 h' cols], gate rows
// {j*32.., 512+j*32.., 1024+j*32..} of gh = h_prev @ W_hh^T, gi recomputed
// from x on the fly (K=27), and fuses decode of logits[:, t-1, v] for
// v in {2j, 2j+1} (h_prev rows are already staged in LDS for the matmul).
__global__ __launch_bounds__(256) void gru_step(
    const float* __restrict__ x,
    const float* __restrict__ W_ih,
    const float* __restrict__ W_hh,
    const float* __restrict__ b_ih,
    const float* __restrict__ b_hh,
    const float* __restrict__ W_dec,
    const float* __restrict__ b_dec,
    const float* __restrict__ h_prev,
    float* __restrict__ h_next,
    float* __restrict__ out,
    int t)
{
    // stride 76 floats: 304 B = 19*16 -> float4-aligned rows, 4-way bank spread
    __shared__ float hs[32][76];
    __shared__ float ws[96][76];
    __shared__ float xs[32][28];
    __shared__ float wi[96][28];
    __shared__ float bihs[96];
    __shared__ float bhhs[96];

    const int tid = threadIdx.x;
    const int bt  = blockIdx.x;   // batch tile
    const int j   = blockIdx.y;   // h' tile
    const int b0  = bt * 32;
    const int j32 = j * 32;

    // ---- stage x tile, W_ih rows, biases (once per step) ----
    for (int i = tid; i < 32 * Vsz; i += 256) {
        int r = i / Vsz, v = i - r * Vsz;
        xs[r][v] = x[(size_t)(b0 + r) * (Tsz * Vsz) + (size_t)t * Vsz + v];
    }
    for (int i = tid; i < 96 * Vsz; i += 256) {
        int r = i / Vsz, v = i - r * Vsz;
        int g = (r < 32) ? (j32 + r) : ((r < 64) ? (Hsz + j32 + r - 32) : (2 * Hsz + j32 + r - 64));
        wi[r][v] = W_ih[g * Vsz + v];
    }
    if (tid < 96) {
        int g = (tid < 32) ? (j32 + tid) : ((tid < 64) ? (Hsz + j32 + tid - 32) : (2 * Hsz + j32 + tid - 64));
        bihs[tid] = b_ih[g];
        bhhs[tid] = b_hh[g];
    }

    const int hp = tid & 31;          // h' within tile (lane dim)
    const int bq = (tid >> 5) << 2;   // 4 batch rows per thread

    float accr[4] = {0.f, 0.f, 0.f, 0.f};
    float accz[4] = {0.f, 0.f, 0.f, 0.f};
    float accn[4] = {0.f, 0.f, 0.f, 0.f};
    float hkeep[4] = {0.f, 0.f, 0.f, 0.f};
    float dec = 0.f;
    const int decb = tid & 31;
    const int decv = j * 2 + (tid >> 5);   // meaningful only for tid < 64

    for (int kc = 0; kc < Hsz; kc += 64) {
        __syncthreads();
        // stage h_prev chunk (32 x 64)
        #pragma unroll
        for (int i = 0; i < 2; ++i) {
            int l = tid + i * 256;
            int r = l >> 4, c = (l & 15) << 2;
            *(float4*)&hs[r][c] = *(const float4*)&h_prev[(size_t)(b0 + r) * Hsz + kc + c];
        }
        // stage W_hh chunk (96 rows x 64)
        #pragma unroll
        for (int i = 0; i < 6; ++i) {
            int l = tid + i * 256;
            int r = l >> 4, c = (l & 15) << 2;
            int g = (r < 32) ? (j32 + r) : ((r < 64) ? (Hsz + j32 + r - 32) : (2 * Hsz + j32 + r - 64));
            *(float4*)&ws[r][c] = *(const float4*)&W_hh[(size_t)g * Hsz + kc + c];
        }
        __syncthreads();

        // grab h_prev at this block's own h' slice for the z-blend
        if (kc == ((j >> 1) << 6)) {
            int off = (j & 1) * 32;
            #pragma unroll
            for (int q = 0; q < 4; ++q) hkeep[q] = hs[bq + q][off + hp];
        }

        #pragma unroll
        for (int k4 = 0; k4 < 64; k4 += 4) {
            float4 wr = *(const float4*)&ws[hp][k4];
            float4 wz = *(const float4*)&ws[32 + hp][k4];
            float4 wn = *(const float4*)&ws[64 + hp][k4];
            #pragma unroll
            for (int q = 0; q < 4; ++q) {
                float4 hv = *(const float4*)&hs[bq + q][k4];
                accr[q] += hv.x * wr.x + hv.y * wr.y + hv.z * wr.z + hv.w * wr.w;
                accz[q] += hv.x * wz.x + hv.y * wz.y + hv.z * wz.z + hv.w * wz.w;
                accn[q] += hv.x * wn.x + hv.y * wn.y + hv.z * wn.z + hv.w * wn.w;
            }
        }

        // fused decode of previous hidden state (writes logits[:, t-1, :])
        if (t > 0 && tid < 64 && decv < Vsz) {
            const float* wd = &W_dec[decv * Hsz + kc];
            #pragma unroll
            for (int k4 = 0; k4 < 64; k4 += 4) {
                float4 hv = *(const float4*)&hs[decb][k4];
                float4 wv = *(const float4*)&wd[k4];
                dec += hv.x * wv.x + hv.y * wv.y + hv.z * wv.z + hv.w * wv.w;
            }
        }
    }

    // ---- gates ----
    #pragma unroll
    for (int q = 0; q < 4; ++q) {
        int b = bq + q;
        float gir = bihs[hp], giz = bihs[32 + hp], gin = bihs[64 + hp];
        #pragma unroll
        for (int v = 0; v < Vsz; ++v) {
            float xv = xs[b][v];
            gir += xv * wi[hp][v];
            giz += xv * wi[32 + hp][v];
            gin += xv * wi[64 + hp][v];
        }
        float ghr = accr[q] + bhhs[hp];
        float ghz = accz[q] + bhhs[32 + hp];
        float ghn = accn[q] + bhhs[64 + hp];
        float rg = 1.f / (1.f + expf(-(gir + ghr)));
        float zg = 1.f / (1.f + expf(-(giz + ghz)));
        float ng = tanhf(gin + rg * ghn);
        float hn = (1.f - zg) * ng + zg * hkeep[q];
        h_next[(size_t)(b0 + b) * Hsz + j32 + hp] = hn;
    }

    if (t > 0 && tid < 64 && decv < Vsz) {
        out[(size_t)(b0 + decb) * (Tsz * Vsz) + (size_t)(t - 1) * Vsz + decv] = dec + b_dec[decv];
    }
}

// ---- decode the final hidden state (t = T-1) ----
__global__ __launch_bounds__(256) void decode_last(
    const float* __restrict__ h,
    const float* __restrict__ W_dec,
    const float* __restrict__ b_dec,
    float* __restrict__ out)
{
    __shared__ float hsd[32][260];
    const int tid = threadIdx.x;
    const int b0 = blockIdx.x * 32;
    const int b = tid & 31;
    const int vg = tid >> 5;
    float acc[4] = {0.f, 0.f, 0.f, 0.f};
    for (int kc = 0; kc < Hsz; kc += 256) {
        __syncthreads();
        #pragma unroll
        for (int i = 0; i < 8; ++i) {
            int l = tid + i * 256;
            int r = l >> 6, c = (l & 63) << 2;
            *(float4*)&hsd[r][c] = *(const float4*)&h[(size_t)(b0 + r) * Hsz + kc + c];
        }
        __syncthreads();
        #pragma unroll
        for (int q = 0; q < 4; ++q) {
            int v = vg + q * 8;
            if (v < Vsz) {
                const float* wd = &W_dec[v * Hsz + kc];
                float a = 0.f;
                for (int k = 0; k < 256; ++k) a += hsd[b][k] * wd[k];
                acc[q] += a;
            }
        }
    }
    #pragma unroll
    for (int q = 0; q < 4; ++q) {
        int v = vg + q * 8;
        if (v < Vsz)
            out[(size_t)(b0 + b) * (Tsz * Vsz) + (size_t)(Tsz - 1) * Vsz + v] = acc[q] + b_dec[v];
    }
}

__global__ void init_h(float* __restrict__ h)
{
    int i = blockIdx.x * 256 + threadIdx.x;
    *(float4*)&h[(size_t)i * 4] = make_float4(0.f, 0.f, 0.f, 0.f);
}

extern "C" void kernel_launch(void* const* d_in, const int* in_sizes, int n_in,
                              void* d_out, int out_size, void* d_ws, size_t ws_size,
                              hipStream_t stream) {
    const float* x     = (const float*)d_in[0];
    const float* W_ih  = (const float*)d_in[1];
    const float* W_hh  = (const float*)d_in[2];
    const float* b_ih  = (const float*)d_in[3];
    const float* b_hh  = (const float*)d_in[4];
    const float* W_dec = (const float*)d_in[5];
    const float* b_dec = (const float*)d_in[6];
    float* out  = (float*)d_out;
    float* hbuf = (float*)d_ws;   // double-buffered h: 2 x 512x512 fp32 = 2 MB

    // zero h buffer 0 (read at t=0)
    init_h<<<256, 256, 0, stream>>>(hbuf);

    dim3 grid(16, 16);
    for (int t = 0; t < Tsz; ++t) {
        float* hp = hbuf + (size_t)(t & 1) * (Hsz * Bsz / 1) * 1;  // buf t&1
        float* hn = hbuf + (size_t)((t + 1) & 1) * (Bsz * Hsz);
        hp = hbuf + (size_t)(t & 1) * (Bsz * Hsz);
        gru_step<<<grid, 256, 0, stream>>>(x, W_ih, W_hh, b_ih, b_hh, W_dec, b_dec,
                                           hp, hn, out, t);
    }
    // final h lives in buf[(1023+1)&1] = buf 0
    decode_last<<<16, 256, 0, stream>>>(hbuf, W_dec, b_dec, out);
}